// Round 12
// baseline (157.730 us; speedup 1.0000x reference)
//
#include <hip/hip_runtime.h>
#include <hip/hip_bf16.h>
#include <stdint.h>
#include <math.h>

#define SEQ   1024
#define NHEAD 12
#define HD    64
#define CDIM  768
#define MTOK  8192
#define NQKV  2304
#define NPAIR 96   // BS*NHEAD

// q pre-scale: 1/sqrt(64) * log2(e)  (softmax done base-2)
#define QSCALE 0.18033688011112042f

typedef uint16_t u16;
typedef __attribute__((ext_vector_type(8)))  __bf16 bf16x8;
typedef __attribute__((ext_vector_type(4)))  float  f32x4;
typedef __attribute__((ext_vector_type(16))) float  f32x16;

__device__ __forceinline__ u16 f32_to_bf16(float f) {
  union { float f; uint32_t u; } cv; cv.f = f;
  uint32_t u = cv.u;
  return (u16)((u + 0x7FFFu + ((u >> 16) & 1u)) >> 16);
}

__device__ __forceinline__ uint32_t cvt_pk_bf16(float lo, float hi) {
  uint32_t r;
  asm("v_cvt_pk_bf16_f32 %0, %1, %2" : "=v"(r) : "v"(lo), "v"(hi));
  return r;
}

// v_permlane32_swap_b32: a.hi <-> b.lo
__device__ __forceinline__ void pl32_swap(uint32_t& a, uint32_t& b) {
  asm("v_permlane32_swap_b32 %0, %1" : "+v"(a), "+v"(b));
}

__device__ __forceinline__ float vexp2(float x) {
  float r; asm("v_exp_f32 %0, %1" : "=v"(r) : "v"(x)); return r;
}
__device__ __forceinline__ float vmax3(float a, float b, float c) {
  float d; asm("v_max3_f32 %0, %1, %2, %3" : "=v"(d) : "v"(a), "v"(b), "v"(c)); return d;
}
__device__ __forceinline__ float vrcp(float x) {
  float r; asm("v_rcp_f32 %0, %1" : "=v"(r) : "v"(x)); return r;
}

__device__ __forceinline__ void load_lds16(const u16* g, u16* l) {
  __builtin_amdgcn_global_load_lds(
      (const __attribute__((address_space(1))) uint32_t*)g,
      (__attribute__((address_space(3))) uint32_t*)l, 16, 0, 0);
}

// swizzled LDS read: 16B at (row, col-byte cb) of a 128B-row tile
__device__ __forceinline__ bf16x8 ldsw(const u16* base, int r, int cb) {
  int byte = (r << 7) + cb;
  byte ^= ((r & 7) << 4);
  return *(const bf16x8*)((const char*)base + byte);
}

// stage NB bytes (rows of 128B) from contiguous global, swizzled
template<int NB>
__device__ __forceinline__ void stage_swz(const u16* __restrict__ g, u16* l, int tid) {
  #pragma unroll
  for (int i = 0; i < NB / 4096; ++i) {
    int F = i * 4096 + tid * 16;
    int S = F ^ (((F >> 7) & 7) << 4);
    load_lds16(g + (S >> 1), l + (F >> 1));
  }
}

// stage V^T chunk: global vt[pair][d=64][n=1024], cols kc*64..+63 -> 64x128B tile
__device__ __forceinline__ void stage_vt(const u16* __restrict__ vtb, u16* l, int kc, int tid) {
  #pragma unroll
  for (int i = 0; i < 2; ++i) {
    int F = i * 4096 + tid * 16;
    int S = F ^ (((F >> 7) & 7) << 4);
    int r = S >> 7;
    int cb = S & 127;
    load_lds16(vtb + ((size_t)r << 10) + (kc << 6) + (cb >> 1), l + (F >> 1));
  }
}

// ---- convert x (fp32) -> bf16, 8 elems/thread ----
__global__ __launch_bounds__(256) void cvt_x_kernel(const float* __restrict__ in,
                                                    u16* __restrict__ out) {
  int i = blockIdx.x * 256 + threadIdx.x;
  const float4* p = (const float4*)in + (size_t)i * 2;
  float4 a = p[0], b = p[1];
  uint4 o;
  o.x = cvt_pk_bf16(a.x, a.y);
  o.y = cvt_pk_bf16(a.z, a.w);
  o.z = cvt_pk_bf16(b.x, b.y);
  o.w = cvt_pk_bf16(b.z, b.w);
  ((uint4*)out)[i] = o;
}

// ---- LDS-tiled transpose+convert: in [K][N] fp32 -> out [N][K] bf16 ----
__global__ __launch_bounds__(256) void transpose_cvt_kernel(const float* __restrict__ in,
                                                            u16* __restrict__ out,
                                                            int K, int N) {
  __shared__ u16 t[64][66];
  int nbk = K >> 6;
  int bk = blockIdx.x % nbk, bn = blockIdx.x / nbk;
  int k0 = bk << 6, n0 = bn << 6;
  int tid = threadIdx.x;
  #pragma unroll
  for (int i = 0; i < 16; ++i) {
    int idx = i * 256 + tid;
    int kr = idx >> 6, nc = idx & 63;
    t[kr][nc] = f32_to_bf16(in[(size_t)(k0 + kr) * N + n0 + nc]);
  }
  __syncthreads();
  #pragma unroll
  for (int i = 0; i < 16; ++i) {
    int idx = i * 256 + tid;
    int nr = idx >> 6, kc = idx & 63;
    out[(size_t)(n0 + nr) * K + k0 + kc] = t[kc][nr];
  }
}

// ---- QKV GEMM: 256x256 tile, BK=64, 8 waves, 4 fine phases per K-tile ----
// m201-style: per phase {ds_read quadrant frags || stage 1 half-tile ->
// setprio(1) 16 MFMA setprio(0) -> raw barrier}; counted vmcnt(2) once per
// K-tile (never drains mid-loop). 128KB dynamic LDS, dbuf by K-tile parity.
__global__ __launch_bounds__(512, 1) void gemm256_qkv(const u16* __restrict__ A,
                                                      const u16* __restrict__ Bt,
                                                      u16* __restrict__ qb,
                                                      u16* __restrict__ kb,
                                                      u16* __restrict__ vb) {
  extern __shared__ u16 lds[];
  const int K = CDIM;                          // 768 -> 12 K-tiles
  int bid = blockIdx.x;
  int wgid = (bid & 7) * 36 + (bid >> 3);      // 288 blocks, bijective XCD swizzle
  int tm = wgid / 9, tn = wgid - tm * 9;
  int mBase = tm << 8, nBase = tn << 8;
  int tid = threadIdx.x;
  int lane = tid & 63, wid = tid >> 6;
  int wm = wid >> 2, wn = wid & 3;             // 2M x 4N waves; 128x64 out/wave
  int lr = lane & 15, lk = lane >> 4;

  // A buffers: elems [0,16384) kt-even, [16384,32768) kt-odd; B at +32768
  auto STAGE_A = [&](int kt, int h) {
    u16* dst = lds + (kt & 1) * 16384 + h * 8192;
    #pragma unroll
    for (int i = 0; i < 2; ++i) {
      int F = i * 8192 + tid * 16;             // byte within 16KB half
      int row = h * 128 + (F >> 7);
      int cb  = (F & 127) ^ (((F >> 7) & 7) << 4);
      load_lds16(A + (size_t)(mBase + row) * K + kt * 64 + (cb >> 1), dst + (F >> 1));
    }
  };
  auto STAGE_B = [&](int kt, int h) {
    u16* dst = lds + 32768 + (kt & 1) * 16384 + h * 8192;
    #pragma unroll
    for (int i = 0; i < 2; ++i) {
      int F = i * 8192 + tid * 16;
      int row = h * 128 + (F >> 7);
      int cb  = (F & 127) ^ (((F >> 7) & 7) << 4);
      load_lds16(Bt + (size_t)(nBase + row) * K + kt * 64 + (cb >> 1), dst + (F >> 1));
    }
  };

  f32x4 acc[8][4] = {};

  auto PHASE = [&](const u16* as, const u16* bs, int qm, int qn) {
    bf16x8 af[4][2], bfv[2][2];
    #pragma unroll
    for (int kk = 0; kk < 2; ++kk) {
      #pragma unroll
      for (int mi = 0; mi < 4; ++mi)
        af[mi][kk] = ldsw(as, wm * 128 + qm * 64 + mi * 16 + lr, kk * 64 + lk * 16);
      #pragma unroll
      for (int ni = 0; ni < 2; ++ni)
        bfv[ni][kk] = ldsw(bs, wn * 64 + qn * 32 + ni * 16 + lr, kk * 64 + lk * 16);
    }
    __builtin_amdgcn_s_setprio(1);
    #pragma unroll
    for (int kk = 0; kk < 2; ++kk)
      #pragma unroll
      for (int mi = 0; mi < 4; ++mi)
        #pragma unroll
        for (int ni = 0; ni < 2; ++ni)
          acc[qm * 4 + mi][qn * 2 + ni] =
              __builtin_amdgcn_mfma_f32_16x16x32_bf16(af[mi][kk], bfv[ni][kk],
                                                      acc[qm * 4 + mi][qn * 2 + ni], 0, 0, 0);
    __builtin_amdgcn_s_setprio(0);
  };

  // prologue: stage K-tile 0 (8 loads outstanding)
  STAGE_A(0, 0); STAGE_A(0, 1); STAGE_B(0, 0); STAGE_B(0, 1);

  for (int kt = 0; kt < 12; ++kt) {
    const u16* as = lds + (kt & 1) * 16384;
    const u16* bs = lds + 32768 + (kt & 1) * 16384;
    const bool st = (kt + 1) < 12;

    // phase 0: stage A-half0(kt+1); wait kt's 8 loads; barrier; quadrant (0,0)
    if (st) {
      STAGE_A(kt + 1, 0);
      asm volatile("s_waitcnt vmcnt(2)" ::: "memory");
    } else {
      asm volatile("s_waitcnt vmcnt(0)" ::: "memory");
    }
    __builtin_amdgcn_s_barrier();
    asm volatile("" ::: "memory");
    PHASE(as, bs, 0, 0);
    __builtin_amdgcn_s_barrier();

    // phase 1
    if (st) STAGE_A(kt + 1, 1);
    PHASE(as, bs, 0, 1);
    __builtin_amdgcn_s_barrier();

    // phase 2
    if (st) STAGE_B(kt + 1, 0);
    PHASE(as, bs, 1, 0);
    __builtin_amdgcn_s_barrier();

    // phase 3
    if (st) STAGE_B(kt + 1, 1);
    PHASE(as, bs, 1, 1);
    __builtin_amdgcn_s_barrier();    // iter-end: all reads of buf[kt&1] done
    asm volatile("" ::: "memory");   // next iter stages into it
  }

  // epilogue: scatter q (pre-scaled) / k [pair][n][d], vT [pair][d][n]
  #pragma unroll
  for (int mi = 0; mi < 8; ++mi)
    #pragma unroll
    for (int ni = 0; ni < 4; ++ni)
      #pragma unroll
      for (int j = 0; j < 4; ++j) {
        int m = mBase + wm * 128 + mi * 16 + lk * 4 + j;
        int c = nBase + wn * 64 + ni * 16 + lr;
        float val = acc[mi][ni][j];
        int s = c / CDIM, rem = c - s * CDIM;
        int h = rem >> 6, d = rem & 63;
        int bb = m >> 10, nn = m & 1023;
        size_t pbase = ((size_t)(bb * NHEAD + h)) << 16;
        if (s == 0)      qb[pbase + (nn << 6) + d] = f32_to_bf16(val * QSCALE);
        else if (s == 1) kb[pbase + (nn << 6) + d] = f32_to_bf16(val);
        else             vb[pbase + ((size_t)d << 10) + nn] = f32_to_bf16(val);
      }
}

// ---- bf16 GEMM (w_o projection), 128x128 tile, BK=64, 4 waves (r10 best) ----
__global__ __launch_bounds__(256) void gemm_bt(const u16* __restrict__ A,
                                               const u16* __restrict__ Bt,
                                               float* __restrict__ Cf,
                                               int M, int N, int K, int cpx) {
  __shared__ u16 As[2][128 * 64];
  __shared__ u16 Bs[2][128 * 64];

  int bid = blockIdx.x;
  int wgid = (bid & 7) * cpx + (bid >> 3);
  const int ntn = N >> 7;
  int tm = wgid / ntn, tn = wgid - tm * ntn;
  int mBase = tm << 7, nBase = tn << 7;
  int tid = threadIdx.x;
  int lane = tid & 63, wid = tid >> 6;
  int wr = (wid >> 1) << 6, wc = (wid & 1) << 6;
  int lr = lane & 15, lk = lane >> 4;

  const int nk = K >> 6;

  auto STAGE = [&](int kt, int b) {
    #pragma unroll
    for (int i = 0; i < 4; ++i) {
      int F = i * 4096 + tid * 16;
      int row = F >> 7;
      int cb  = (F & 127) ^ ((row & 7) << 4);
      load_lds16(A + (size_t)(mBase + row) * K + kt * 64 + (cb >> 1), &As[b][F >> 1]);
    }
    #pragma unroll
    for (int i = 0; i < 4; ++i) {
      int F = i * 4096 + tid * 16;
      int row = F >> 7;
      int cb  = (F & 127) ^ ((row & 7) << 4);
      load_lds16(Bt + (size_t)(nBase + row) * K + kt * 64 + (cb >> 1), &Bs[b][F >> 1]);
    }
  };

  f32x4 acc[4][4] = {};

  STAGE(0, 0);
  for (int kt = 0; kt < nk; ++kt) {
    const int cur = kt & 1;
    if (kt + 1 < nk) {
      STAGE(kt + 1, cur ^ 1);
      asm volatile("s_waitcnt vmcnt(8)" ::: "memory");
    } else {
      asm volatile("s_waitcnt vmcnt(0)" ::: "memory");
    }
    __builtin_amdgcn_s_barrier();
    asm volatile("" ::: "memory");

    #pragma unroll
    for (int kk = 0; kk < 2; ++kk) {
      bf16x8 af[4], bfr[4];
      #pragma unroll
      for (int i = 0; i < 4; ++i)
        af[i]  = ldsw(As[cur], wr + i * 16 + lr, kk * 64 + lk * 16);
      #pragma unroll
      for (int i = 0; i < 4; ++i)
        bfr[i] = ldsw(Bs[cur], wc + i * 16 + lr, kk * 64 + lk * 16);
      #pragma unroll
      for (int mi = 0; mi < 4; ++mi)
        #pragma unroll
        for (int ni = 0; ni < 4; ++ni)
          acc[mi][ni] = __builtin_amdgcn_mfma_f32_16x16x32_bf16(af[mi], bfr[ni], acc[mi][ni], 0, 0, 0);
    }

    __builtin_amdgcn_s_barrier();
    asm volatile("" ::: "memory");
  }

  #pragma unroll
  for (int mi = 0; mi < 4; ++mi)
    #pragma unroll
    for (int ni = 0; ni < 4; ++ni)
      #pragma unroll
      for (int j = 0; j < 4; ++j) {
        int m = mBase + wr + mi * 16 + lk * 4 + j;
        int c = nBase + wc + ni * 16 + lr;
        Cf[(size_t)m * N + c] = acc[mi][ni][j];
      }
}

// ---- flash attention v7 (r11, kept): 32x32 swapped QK^T, in-register P,
// counted vmcnt(4), VALU diet (v_max3/v_exp), l via ones-MFMA ----
__global__ __launch_bounds__(256) void attn_kernel(const u16* __restrict__ q,
                                                   const u16* __restrict__ k,
                                                   const u16* __restrict__ v,
                                                   u16* __restrict__ out) {
  __shared__ u16 Ks[2][64 * 64];
  __shared__ u16 Vs[2][64 * 64];    // V^T chunks: [d=64][k=64]

  int bid = blockIdx.x;
  int wgid = (bid & 7) * 96 + (bid >> 3);   // 768 blocks, 96/XCD -> pairs XCD-local
  int pair = wgid >> 3;
  int qt   = wgid & 7;                      // 8 q-tiles of 128 rows
  int b = pair / NHEAD, hh = pair - b * NHEAD;
  const u16* Kg  = k + ((size_t)pair << 16);
  const u16* Vtb = v + ((size_t)pair << 16);
  int tid = threadIdx.x, lane = tid & 63, wid = tid >> 6;
  int ql = lane & 31, hi = lane >> 5;

  const u16* Qrow = q + ((size_t)pair << 16) + (size_t)((qt << 7) + (wid << 5) + ql) * 64;
  bf16x8 qf[4];
  #pragma unroll
  for (int t = 0; t < 4; ++t)
    qf[t] = *(const bf16x8*)(Qrow + t * 16 + hi * 8);

  bf16x8 onesv;
  { union { uint32_t u[4]; bf16x8 v8; } ou;
    ou.u[0] = ou.u[1] = ou.u[2] = ou.u[3] = 0x3F803F80u; onesv = ou.v8; }

  stage_swz<8192>(Kg, Ks[0], tid);
  stage_vt(Vtb, Vs[0], 0, tid);

  float m_ = -1e30f;
  f32x16 acc0 = {}, acc1 = {};
  f32x16 accL = {};

  for (int kc = 0; kc < 16; ++kc) {
    const int cur = kc & 1;
    if (kc < 15) {
      stage_swz<8192>(Kg + ((kc + 1) << 12), Ks[cur ^ 1], tid);
      stage_vt(Vtb, Vs[cur ^ 1], kc + 1, tid);
      asm volatile("s_waitcnt vmcnt(4)" ::: "memory");
    } else {
      asm volatile("s_waitcnt vmcnt(0)" ::: "memory");
    }
    __builtin_amdgcn_s_barrier();
    asm volatile("" ::: "memory");

    f32x16 s0 = {}, s1 = {};
    __builtin_amdgcn_s_setprio(1);
    #pragma unroll
    for (int t = 0; t < 4; ++t) {
      bf16x8 k0 = ldsw(Ks[cur], ql,      t * 32 + hi * 16);
      s0 = __builtin_amdgcn_mfma_f32_32x32x16_bf16(k0, qf[t], s0, 0, 0, 0);
      bf16x8 k1 = ldsw(Ks[cur], 32 + ql, t * 32 + hi * 16);
      s1 = __builtin_amdgcn_mfma_f32_32x32x16_bf16(k1, qf[t], s1, 0, 0, 0);
    }
    __builtin_amdgcn_s_setprio(0);

    float a0 = vmax3(s0[0],  s0[1],  s0[2]);
    float a1 = vmax3(s0[3],  s0[4],  s0[5]);
    float a2 = vmax3(s0[6],  s0[7],  s0[8]);
    float a3 = vmax3(s0[9],  s0[10], s0[11]);
    float a4 = vmax3(s0[12], s0[13], s0[14]);
    float a5 = vmax3(s0[15], s1[0],  s1[1]);
    float a6 = vmax3(s1[2],  s1[3],  s1[4]);
    float a7 = vmax3(s1[5],  s1[6],  s1[7]);
    float a8 = vmax3(s1[8],  s1[9],  s1[10]);
    float a9 = vmax3(s1[11], s1[12], s1[13]);
    float aA = fmaxf(s1[14], s1[15]);
    float b0 = vmax3(a0, a1, a2);
    float b1 = vmax3(a3, a4, a5);
    float b2 = vmax3(a6, a7, a8);
    float b3 = vmax3(a9, aA, b0);
    float pm = vmax3(b1, b2, b3);

    if (!__all(pm - m_ <= 8.f)) {
      float om = fmaxf(pm, __shfl_xor(pm, 32, 64));
      float newm = fmaxf(m_, om);
      float alpha = vexp2(m_ - newm);
      m_ = newm;
      #pragma unroll
      for (int r = 0; r < 16; ++r) {
        int qr = (r & 3) + 8 * (r >> 2) + 4 * hi;
        float ar = __shfl(alpha, qr, 32);
        acc0[r] *= ar;
        acc1[r] *= ar;
        accL[r] *= ar;
      }
    }

    f32x16 mv;
    #pragma unroll
    for (int r = 0; r < 16; ++r) mv[r] = m_;
    f32x16 d0 = s0 - mv, d1 = s1 - mv;
    #pragma unroll
    for (int r = 0; r < 16; ++r) s0[r] = vexp2(d0[r]);
    #pragma unroll
    for (int r = 0; r < 16; ++r) s1[r] = vexp2(d1[r]);

    __builtin_amdgcn_s_setprio(1);
    #pragma unroll
    for (int t = 0; t < 4; ++t) {
      const int base = (t & 1) * 8;
      uint32_t wA, wB, wC, wD;
      if (t < 2) {
        wA = cvt_pk_bf16(s0[base + 0], s0[base + 1]);
        wB = cvt_pk_bf16(s0[base + 2], s0[base + 3]);
        wC = cvt_pk_bf16(s0[base + 4], s0[base + 5]);
        wD = cvt_pk_bf16(s0[base + 6], s0[base + 7]);
      } else {
        wA = cvt_pk_bf16(s1[base + 0], s1[base + 1]);
        wB = cvt_pk_bf16(s1[base + 2], s1[base + 3]);
        wC = cvt_pk_bf16(s1[base + 4], s1[base + 5]);
        wD = cvt_pk_bf16(s1[base + 6], s1[base + 7]);
      }
      pl32_swap(wA, wC);
      pl32_swap(wB, wD);
      union { uint32_t u[4]; bf16x8 v8; } pu;
      pu.u[0] = wA; pu.u[1] = wB; pu.u[2] = wC; pu.u[3] = wD;
      bf16x8 v0 = ldsw(Vs[cur], ql,      t * 32 + hi * 16);
      acc0 = __builtin_amdgcn_mfma_f32_32x32x16_bf16(pu.v8, v0, acc0, 0, 0, 0);
      bf16x8 v1 = ldsw(Vs[cur], 32 + ql, t * 32 + hi * 16);
      acc1 = __builtin_amdgcn_mfma_f32_32x32x16_bf16(pu.v8, v1, acc1, 0, 0, 0);
      accL = __builtin_amdgcn_mfma_f32_32x32x16_bf16(pu.v8, onesv, accL, 0, 0, 0);
    }
    __builtin_amdgcn_s_setprio(0);

    __builtin_amdgcn_s_barrier();
    asm volatile("" ::: "memory");
  }

  u16* ob = out + ((size_t)(b * SEQ + (qt << 7) + (wid << 5))) * CDIM + hh * 64 + ql;
  #pragma unroll
  for (int r = 0; r < 16; ++r) {
    int qr = (r & 3) + 8 * (r >> 2) + 4 * hi;
    float ilr = vrcp(accL[r]);
    ob[(size_t)qr * CDIM]      = f32_to_bf16(acc0[r] * ilr);
    ob[(size_t)qr * CDIM + 32] = f32_to_bf16(acc1[r] * ilr);
  }
}

extern "C" void kernel_launch(void* const* d_in, const int* in_sizes, int n_in,
                              void* d_out, int out_size, void* d_ws, size_t ws_size,
                              hipStream_t stream) {
  const float* x     = (const float*)d_in[0];
  const float* w_qkv = (const float*)d_in[1];
  const float* w_o   = (const float*)d_in[2];
  float* out = (float*)d_out;

  u16* xb    = (u16*)d_ws;
  u16* wqkvT = xb    + (size_t)MTOK * CDIM;
  u16* woT   = wqkvT + (size_t)NQKV * CDIM;
  u16* qb    = woT   + (size_t)CDIM * CDIM;
  u16* kb    = qb    + (size_t)NPAIR * SEQ * HD;
  u16* vb    = kb    + (size_t)NPAIR * SEQ * HD;   // stored transposed: [pair][d][n]
  u16* ao    = vb    + (size_t)NPAIR * SEQ * HD;

  (void)hipFuncSetAttribute((const void*)gemm256_qkv,
                            hipFuncAttributeMaxDynamicSharedMemorySize, 131072);

  cvt_x_kernel<<<dim3((MTOK * CDIM) / (256 * 8)), 256, 0, stream>>>(x, xb);
  transpose_cvt_kernel<<<dim3((CDIM / 64) * (NQKV / 64)), 256, 0, stream>>>(w_qkv, wqkvT, CDIM, NQKV);
  transpose_cvt_kernel<<<dim3((CDIM / 64) * (CDIM / 64)), 256, 0, stream>>>(w_o, woT, CDIM, CDIM);

  gemm256_qkv<<<dim3(288), 512, 131072, stream>>>(xb, wqkvT, qb, kb, vb);

  attn_kernel<<<dim3(NPAIR * 8), 256, 0, stream>>>(qb, kb, vb, ao);

  {
    int nwg = (MTOK / 128) * (CDIM / 128);   // 384, %8==0
    gemm_bt<<<dim3(nwg), 256, 0, stream>>>(
        ao, woT, out, MTOK, CDIM, CDIM, nwg / 8);
  }
}

// Round 13
// 137.301 us; speedup vs baseline: 1.1488x; 1.1488x over previous
//
#include <hip/hip_runtime.h>
#include <hip/hip_bf16.h>
#include <stdint.h>
#include <math.h>

#define SEQ   1024
#define NHEAD 12
#define HD    64
#define CDIM  768
#define MTOK  8192
#define NQKV  2304
#define NPAIR 96   // BS*NHEAD

// q pre-scale: 1/sqrt(64) * log2(e)  (softmax done base-2)
#define QSCALE 0.18033688011112042f

typedef uint16_t u16;
typedef __attribute__((ext_vector_type(8)))  __bf16 bf16x8;
typedef __attribute__((ext_vector_type(4)))  float  f32x4;
typedef __attribute__((ext_vector_type(16))) float  f32x16;

__device__ __forceinline__ u16 f32_to_bf16(float f) {
  union { float f; uint32_t u; } cv; cv.f = f;
  uint32_t u = cv.u;
  return (u16)((u + 0x7FFFu + ((u >> 16) & 1u)) >> 16);
}

__device__ __forceinline__ uint32_t cvt_pk_bf16(float lo, float hi) {
  uint32_t r;
  asm("v_cvt_pk_bf16_f32 %0, %1, %2" : "=v"(r) : "v"(lo), "v"(hi));
  return r;
}

// v_permlane32_swap_b32: a.hi <-> b.lo
__device__ __forceinline__ void pl32_swap(uint32_t& a, uint32_t& b) {
  asm("v_permlane32_swap_b32 %0, %1" : "+v"(a), "+v"(b));
}

__device__ __forceinline__ float vexp2(float x) {
  float r; asm("v_exp_f32 %0, %1" : "=v"(r) : "v"(x)); return r;
}
__device__ __forceinline__ float vmax3(float a, float b, float c) {
  float d; asm("v_max3_f32 %0, %1, %2, %3" : "=v"(d) : "v"(a), "v"(b), "v"(c)); return d;
}
__device__ __forceinline__ float vrcp(float x) {
  float r; asm("v_rcp_f32 %0, %1" : "=v"(r) : "v"(x)); return r;
}

__device__ __forceinline__ void load_lds16(const u16* g, u16* l) {
  __builtin_amdgcn_global_load_lds(
      (const __attribute__((address_space(1))) uint32_t*)g,
      (__attribute__((address_space(3))) uint32_t*)l, 16, 0, 0);
}

// swizzled LDS read: 16B at (row, col-byte cb) of a 128B-row tile
__device__ __forceinline__ bf16x8 ldsw(const u16* base, int r, int cb) {
  int byte = (r << 7) + cb;
  byte ^= ((r & 7) << 4);
  return *(const bf16x8*)((const char*)base + byte);
}

// stage NB bytes (rows of 128B) from contiguous global, swizzled
template<int NB>
__device__ __forceinline__ void stage_swz(const u16* __restrict__ g, u16* l, int tid) {
  #pragma unroll
  for (int i = 0; i < NB / 4096; ++i) {
    int F = i * 4096 + tid * 16;
    int S = F ^ (((F >> 7) & 7) << 4);
    load_lds16(g + (S >> 1), l + (F >> 1));
  }
}

// stage V^T chunk: global vt[pair][d=64][n=1024], cols kc*64..+63 -> 64x128B tile
__device__ __forceinline__ void stage_vt(const u16* __restrict__ vtb, u16* l, int kc, int tid) {
  #pragma unroll
  for (int i = 0; i < 2; ++i) {
    int F = i * 4096 + tid * 16;
    int S = F ^ (((F >> 7) & 7) << 4);
    int r = S >> 7;
    int cb = S & 127;
    load_lds16(vtb + ((size_t)r << 10) + (kc << 6) + (cb >> 1), l + (F >> 1));
  }
}

// ---- convert x (fp32) -> bf16, 8 elems/thread ----
__global__ __launch_bounds__(256) void cvt_x_kernel(const float* __restrict__ in,
                                                    u16* __restrict__ out) {
  int i = blockIdx.x * 256 + threadIdx.x;
  const float4* p = (const float4*)in + (size_t)i * 2;
  float4 a = p[0], b = p[1];
  uint4 o;
  o.x = cvt_pk_bf16(a.x, a.y);
  o.y = cvt_pk_bf16(a.z, a.w);
  o.z = cvt_pk_bf16(b.x, b.y);
  o.w = cvt_pk_bf16(b.z, b.w);
  ((uint4*)out)[i] = o;
}

// ---- LDS-tiled transpose+convert: in [K][N] fp32 -> out [N][K] bf16 ----
__global__ __launch_bounds__(256) void transpose_cvt_kernel(const float* __restrict__ in,
                                                            u16* __restrict__ out,
                                                            int K, int N) {
  __shared__ u16 t[64][66];
  int nbk = K >> 6;
  int bk = blockIdx.x % nbk, bn = blockIdx.x / nbk;
  int k0 = bk << 6, n0 = bn << 6;
  int tid = threadIdx.x;
  #pragma unroll
  for (int i = 0; i < 16; ++i) {
    int idx = i * 256 + tid;
    int kr = idx >> 6, nc = idx & 63;
    t[kr][nc] = f32_to_bf16(in[(size_t)(k0 + kr) * N + n0 + nc]);
  }
  __syncthreads();
  #pragma unroll
  for (int i = 0; i < 16; ++i) {
    int idx = i * 256 + tid;
    int nr = idx >> 6, kc = idx & 63;
    out[(size_t)(n0 + nr) * K + k0 + kc] = t[kc][nr];
  }
}

// ---- bf16 GEMM, A[M][K] @ Bt[N][K]^T, 128x128 tile, BK=64, 4 waves ----
// Double-buffered LDS + counted vmcnt(8) (loads in flight across barriers),
// T2 read swizzle, T1 XCD swizzle. (r10 proven config)
template<int EPI>
__global__ __launch_bounds__(256) void gemm_bt(const u16* __restrict__ A,
                                               const u16* __restrict__ Bt,
                                               float* __restrict__ Cf,
                                               u16* __restrict__ qb,
                                               u16* __restrict__ kb,
                                               u16* __restrict__ vb,
                                               int M, int N, int K, int cpx) {
  __shared__ u16 As[2][128 * 64];
  __shared__ u16 Bs[2][128 * 64];

  int bid = blockIdx.x;
  int wgid = (bid & 7) * cpx + (bid >> 3);
  const int ntn = N >> 7;
  int tm = wgid / ntn, tn = wgid - tm * ntn;
  int mBase = tm << 7, nBase = tn << 7;
  int tid = threadIdx.x;
  int lane = tid & 63, wid = tid >> 6;
  int wr = (wid >> 1) << 6, wc = (wid & 1) << 6;
  int lr = lane & 15, lk = lane >> 4;

  const int nk = K >> 6;

  auto STAGE = [&](int kt, int b) {
    #pragma unroll
    for (int i = 0; i < 4; ++i) {
      int F = i * 4096 + tid * 16;
      int row = F >> 7;
      int cb  = (F & 127) ^ ((row & 7) << 4);
      load_lds16(A + (size_t)(mBase + row) * K + kt * 64 + (cb >> 1), &As[b][F >> 1]);
    }
    #pragma unroll
    for (int i = 0; i < 4; ++i) {
      int F = i * 4096 + tid * 16;
      int row = F >> 7;
      int cb  = (F & 127) ^ ((row & 7) << 4);
      load_lds16(Bt + (size_t)(nBase + row) * K + kt * 64 + (cb >> 1), &Bs[b][F >> 1]);
    }
  };

  f32x4 acc[4][4] = {};

  STAGE(0, 0);
  for (int kt = 0; kt < nk; ++kt) {
    const int cur = kt & 1;
    if (kt + 1 < nk) {
      STAGE(kt + 1, cur ^ 1);
      asm volatile("s_waitcnt vmcnt(8)" ::: "memory");
    } else {
      asm volatile("s_waitcnt vmcnt(0)" ::: "memory");
    }
    __builtin_amdgcn_s_barrier();
    asm volatile("" ::: "memory");

    #pragma unroll
    for (int kk = 0; kk < 2; ++kk) {
      bf16x8 af[4], bfr[4];
      #pragma unroll
      for (int i = 0; i < 4; ++i)
        af[i]  = ldsw(As[cur], wr + i * 16 + lr, kk * 64 + lk * 16);
      #pragma unroll
      for (int i = 0; i < 4; ++i)
        bfr[i] = ldsw(Bs[cur], wc + i * 16 + lr, kk * 64 + lk * 16);
      #pragma unroll
      for (int mi = 0; mi < 4; ++mi)
        #pragma unroll
        for (int ni = 0; ni < 4; ++ni)
          acc[mi][ni] = __builtin_amdgcn_mfma_f32_16x16x32_bf16(af[mi], bfr[ni], acc[mi][ni], 0, 0, 0);
    }

    __builtin_amdgcn_s_barrier();
    asm volatile("" ::: "memory");
  }

  #pragma unroll
  for (int mi = 0; mi < 4; ++mi)
    #pragma unroll
    for (int ni = 0; ni < 4; ++ni)
      #pragma unroll
      for (int j = 0; j < 4; ++j) {
        int m = mBase + wr + mi * 16 + lk * 4 + j;
        int c = nBase + wc + ni * 16 + lr;
        float val = acc[mi][ni][j];
        if (EPI == 0) {
          int s = c / CDIM, rem = c - s * CDIM;
          int h = rem >> 6, d = rem & 63;
          int bb = m >> 10, nn = m & 1023;
          size_t pbase = ((size_t)(bb * NHEAD + h)) << 16;
          if (s == 0)      qb[pbase + (nn << 6) + d] = f32_to_bf16(val * QSCALE);
          else if (s == 1) kb[pbase + (nn << 6) + d] = f32_to_bf16(val);
          else             vb[pbase + ((size_t)d << 10) + nn] = f32_to_bf16(val);
        } else {
          Cf[(size_t)m * N + c] = val;
        }
      }
}

// ---- flash attention v7 (r11, kept): 32x32 swapped QK^T, in-register P,
// counted vmcnt(4), VALU diet (v_max3/v_exp), l via ones-MFMA ----
__global__ __launch_bounds__(256) void attn_kernel(const u16* __restrict__ q,
                                                   const u16* __restrict__ k,
                                                   const u16* __restrict__ v,
                                                   u16* __restrict__ out) {
  __shared__ u16 Ks[2][64 * 64];
  __shared__ u16 Vs[2][64 * 64];    // V^T chunks: [d=64][k=64]

  int bid = blockIdx.x;
  int wgid = (bid & 7) * 96 + (bid >> 3);   // 768 blocks, 96/XCD -> pairs XCD-local
  int pair = wgid >> 3;
  int qt   = wgid & 7;                      // 8 q-tiles of 128 rows
  int b = pair / NHEAD, hh = pair - b * NHEAD;
  const u16* Kg  = k + ((size_t)pair << 16);
  const u16* Vtb = v + ((size_t)pair << 16);
  int tid = threadIdx.x, lane = tid & 63, wid = tid >> 6;
  int ql = lane & 31, hi = lane >> 5;

  const u16* Qrow = q + ((size_t)pair << 16) + (size_t)((qt << 7) + (wid << 5) + ql) * 64;
  bf16x8 qf[4];
  #pragma unroll
  for (int t = 0; t < 4; ++t)
    qf[t] = *(const bf16x8*)(Qrow + t * 16 + hi * 8);

  bf16x8 onesv;
  { union { uint32_t u[4]; bf16x8 v8; } ou;
    ou.u[0] = ou.u[1] = ou.u[2] = ou.u[3] = 0x3F803F80u; onesv = ou.v8; }

  stage_swz<8192>(Kg, Ks[0], tid);
  stage_vt(Vtb, Vs[0], 0, tid);

  float m_ = -1e30f;
  f32x16 acc0 = {}, acc1 = {};
  f32x16 accL = {};

  for (int kc = 0; kc < 16; ++kc) {
    const int cur = kc & 1;
    if (kc < 15) {
      stage_swz<8192>(Kg + ((kc + 1) << 12), Ks[cur ^ 1], tid);
      stage_vt(Vtb, Vs[cur ^ 1], kc + 1, tid);
      asm volatile("s_waitcnt vmcnt(4)" ::: "memory");
    } else {
      asm volatile("s_waitcnt vmcnt(0)" ::: "memory");
    }
    __builtin_amdgcn_s_barrier();
    asm volatile("" ::: "memory");

    f32x16 s0 = {}, s1 = {};
    __builtin_amdgcn_s_setprio(1);
    #pragma unroll
    for (int t = 0; t < 4; ++t) {
      bf16x8 k0 = ldsw(Ks[cur], ql,      t * 32 + hi * 16);
      s0 = __builtin_amdgcn_mfma_f32_32x32x16_bf16(k0, qf[t], s0, 0, 0, 0);
      bf16x8 k1 = ldsw(Ks[cur], 32 + ql, t * 32 + hi * 16);
      s1 = __builtin_amdgcn_mfma_f32_32x32x16_bf16(k1, qf[t], s1, 0, 0, 0);
    }
    __builtin_amdgcn_s_setprio(0);

    float a0 = vmax3(s0[0],  s0[1],  s0[2]);
    float a1 = vmax3(s0[3],  s0[4],  s0[5]);
    float a2 = vmax3(s0[6],  s0[7],  s0[8]);
    float a3 = vmax3(s0[9],  s0[10], s0[11]);
    float a4 = vmax3(s0[12], s0[13], s0[14]);
    float a5 = vmax3(s0[15], s1[0],  s1[1]);
    float a6 = vmax3(s1[2],  s1[3],  s1[4]);
    float a7 = vmax3(s1[5],  s1[6],  s1[7]);
    float a8 = vmax3(s1[8],  s1[9],  s1[10]);
    float a9 = vmax3(s1[11], s1[12], s1[13]);
    float aA = fmaxf(s1[14], s1[15]);
    float b0 = vmax3(a0, a1, a2);
    float b1 = vmax3(a3, a4, a5);
    float b2 = vmax3(a6, a7, a8);
    float b3 = vmax3(a9, aA, b0);
    float pm = vmax3(b1, b2, b3);

    if (!__all(pm - m_ <= 8.f)) {
      float om = fmaxf(pm, __shfl_xor(pm, 32, 64));
      float newm = fmaxf(m_, om);
      float alpha = vexp2(m_ - newm);
      m_ = newm;
      #pragma unroll
      for (int r = 0; r < 16; ++r) {
        int qr = (r & 3) + 8 * (r >> 2) + 4 * hi;
        float ar = __shfl(alpha, qr, 32);
        acc0[r] *= ar;
        acc1[r] *= ar;
        accL[r] *= ar;
      }
    }

    f32x16 mv;
    #pragma unroll
    for (int r = 0; r < 16; ++r) mv[r] = m_;
    f32x16 d0 = s0 - mv, d1 = s1 - mv;
    #pragma unroll
    for (int r = 0; r < 16; ++r) s0[r] = vexp2(d0[r]);
    #pragma unroll
    for (int r = 0; r < 16; ++r) s1[r] = vexp2(d1[r]);

    __builtin_amdgcn_s_setprio(1);
    #pragma unroll
    for (int t = 0; t < 4; ++t) {
      const int base = (t & 1) * 8;
      uint32_t wA, wB, wC, wD;
      if (t < 2) {
        wA = cvt_pk_bf16(s0[base + 0], s0[base + 1]);
        wB = cvt_pk_bf16(s0[base + 2], s0[base + 3]);
        wC = cvt_pk_bf16(s0[base + 4], s0[base + 5]);
        wD = cvt_pk_bf16(s0[base + 6], s0[base + 7]);
      } else {
        wA = cvt_pk_bf16(s1[base + 0], s1[base + 1]);
        wB = cvt_pk_bf16(s1[base + 2], s1[base + 3]);
        wC = cvt_pk_bf16(s1[base + 4], s1[base + 5]);
        wD = cvt_pk_bf16(s1[base + 6], s1[base + 7]);
      }
      pl32_swap(wA, wC);
      pl32_swap(wB, wD);
      union { uint32_t u[4]; bf16x8 v8; } pu;
      pu.u[0] = wA; pu.u[1] = wB; pu.u[2] = wC; pu.u[3] = wD;
      bf16x8 v0 = ldsw(Vs[cur], ql,      t * 32 + hi * 16);
      acc0 = __builtin_amdgcn_mfma_f32_32x32x16_bf16(pu.v8, v0, acc0, 0, 0, 0);
      bf16x8 v1 = ldsw(Vs[cur], 32 + ql, t * 32 + hi * 16);
      acc1 = __builtin_amdgcn_mfma_f32_32x32x16_bf16(pu.v8, v1, acc1, 0, 0, 0);
      accL = __builtin_amdgcn_mfma_f32_32x32x16_bf16(pu.v8, onesv, accL, 0, 0, 0);
    }
    __builtin_amdgcn_s_setprio(0);

    __builtin_amdgcn_s_barrier();
    asm volatile("" ::: "memory");
  }

  u16* ob = out + ((size_t)(b * SEQ + (qt << 7) + (wid << 5))) * CDIM + hh * 64 + ql;
  #pragma unroll
  for (int r = 0; r < 16; ++r) {
    int qr = (r & 3) + 8 * (r >> 2) + 4 * hi;
    float ilr = vrcp(accL[r]);
    ob[(size_t)qr * CDIM]      = f32_to_bf16(acc0[r] * ilr);
    ob[(size_t)qr * CDIM + 32] = f32_to_bf16(acc1[r] * ilr);
  }
}

extern "C" void kernel_launch(void* const* d_in, const int* in_sizes, int n_in,
                              void* d_out, int out_size, void* d_ws, size_t ws_size,
                              hipStream_t stream) {
  const float* x     = (const float*)d_in[0];
  const float* w_qkv = (const float*)d_in[1];
  const float* w_o   = (const float*)d_in[2];
  float* out = (float*)d_out;

  u16* xb    = (u16*)d_ws;
  u16* wqkvT = xb    + (size_t)MTOK * CDIM;
  u16* woT   = wqkvT + (size_t)NQKV * CDIM;
  u16* qb    = woT   + (size_t)CDIM * CDIM;
  u16* kb    = qb    + (size_t)NPAIR * SEQ * HD;
  u16* vb    = kb    + (size_t)NPAIR * SEQ * HD;   // stored transposed: [pair][d][n]
  u16* ao    = vb    + (size_t)NPAIR * SEQ * HD;

  cvt_x_kernel<<<dim3((MTOK * CDIM) / (256 * 8)), 256, 0, stream>>>(x, xb);
  transpose_cvt_kernel<<<dim3((CDIM / 64) * (NQKV / 64)), 256, 0, stream>>>(w_qkv, wqkvT, CDIM, NQKV);
  transpose_cvt_kernel<<<dim3((CDIM / 64) * (CDIM / 64)), 256, 0, stream>>>(w_o, woT, CDIM, CDIM);

  {
    int nwg = (MTOK / 128) * (NQKV / 128);   // 1152, %8==0
    gemm_bt<0><<<dim3(nwg), 256, 0, stream>>>(
        xb, wqkvT, nullptr, qb, kb, vb, MTOK, NQKV, CDIM, nwg / 8);
  }

  attn_kernel<<<dim3(NPAIR * 8), 256, 0, stream>>>(qb, kb, vb, ao);

  {
    int nwg = (MTOK / 128) * (CDIM / 128);   // 384, %8==0
    gemm_bt<1><<<dim3(nwg), 256, 0, stream>>>(
        ao, woT, out, nullptr, nullptr, nullptr, MTOK, CDIM, CDIM, nwg / 8);
  }
}